// Round 15
// baseline (320.389 us; speedup 1.0000x reference)
//
#include <hip/hip_runtime.h>
#include <hip/hip_bf16.h>
#include <stdint.h>

typedef unsigned long long u64;
typedef __hip_bfloat16 bf16;
typedef short s8v __attribute__((ext_vector_type(8)));
typedef short s4v __attribute__((ext_vector_type(4)));
typedef float f4v __attribute__((ext_vector_type(4)));

#define B_   16
#define C_   256
#define N_   1024
#define HID_ 512

// fp32 -> bf16 RNE, bit-level
__device__ __forceinline__ unsigned short f2b(float f) {
    unsigned u = __float_as_uint(f);
    unsigned r = (u + 0x7FFFu + ((u >> 16) & 1u)) >> 16;
    return (unsigned short)r;
}
__device__ __forceinline__ float b2f(unsigned short s) {
    return __uint_as_float(((unsigned)s) << 16);
}
// Runtime-dtype input load: bf==1 -> bf16, bf==0 -> fp32.
__device__ __forceinline__ float ldIn(const void* p, long long i, int bf) {
    return bf ? b2f(((const unsigned short*)p)[i]) : ((const float*)p)[i];
}
__device__ __forceinline__ u64 shfl_xor_u64(u64 v, int m) {
    unsigned lo = (unsigned)v, hi = (unsigned)(v >> 32);
    lo = __shfl_xor(lo, m, 64);
    hi = __shfl_xor(hi, m, 64);
    return ((u64)hi << 32) | lo;
}
__device__ __forceinline__ int probe_bf16(const void* xp) {
    const unsigned short* u = (const unsigned short*)xp;
    int cnt = 0;
    for (int i = 0; i < 64; ++i) {
        int e = (u[2 * i] >> 7) & 0xFF;
        cnt += (e >= 87 && e <= 167);
    }
    return (cnt >= 48) ? 1 : 0;
}

// ---------------------------------------------------------------------------
// Merged prep + weight-cast (gc/fc2 only — fc1 stays fp32-VALU and reads the
// raw input weight). grid 768 x 256. Every block probes dtype locally.
// Block 0 folds BN + publishes flags.
// ---------------------------------------------------------------------------
__global__ __launch_bounds__(256)
void prep_cast(const void* xp,
    const void* wg, const void* w2,
    const void* fc1_b, const void* bn1_g, const void* bn1_b, const void* bn1_m, const void* bn1_v,
    const void* gc_b,  const void* gbn_g, const void* gbn_b, const void* gbn_m, const void* gbn_v,
    const void* bn2_g, const void* bn2_b, const void* bn2_m, const void* bn2_v,
    const void* fc2_b, const void* bn3_g, const void* bn3_b, const void* bn3_m, const void* bn3_v,
    int* flags, float* s1, float* t1, float* Sg, float* Tg, float* s3, float* t3,
    short* Wgb, short* W2b)
{
    __shared__ int sf;
    int t = threadIdx.x, blk = blockIdx.x;
    if (t == 0) sf = probe_bf16(xp);
    __syncthreads();
    int bf = sf;

    if (blk == 0) {
        if (t == 0) flags[0] = bf;
        for (int i = t; i < 512; i += 256) {
            if (i < 256) {
                float g = ldIn(bn1_g, i, bf), bb = ldIn(bn1_b, i, bf);
                float m = ldIn(bn1_m, i, bf), v  = ldIn(bn1_v, i, bf);
                float s = g / sqrtf(v + 1e-5f);
                s1[i] = s;
                t1[i] = (ldIn(fc1_b, i, bf) - m) * s + bb;

                float g3 = ldIn(bn3_g, i, bf), b3 = ldIn(bn3_b, i, bf);
                float m3 = ldIn(bn3_m, i, bf), v3 = ldIn(bn3_v, i, bf);
                float ss3 = g3 / sqrtf(v3 + 1e-5f);
                s3[i] = ss3;
                t3[i] = (ldIn(fc2_b, i, bf) - m3) * ss3 + b3;
            }
            float gg = ldIn(gbn_g, i, bf), gb = ldIn(gbn_b, i, bf);
            float gm = ldIn(gbn_m, i, bf), gv = ldIn(gbn_v, i, bf);
            float sg = gg / sqrtf(gv + 1e-5f);
            float g2 = ldIn(bn2_g, i, bf), b2 = ldIn(bn2_b, i, bf);
            float m2 = ldIn(bn2_m, i, bf), v2 = ldIn(bn2_v, i, bf);
            float s2 = g2 / sqrtf(v2 + 1e-5f);
            Sg[i] = sg * s2;
            Tg[i] = ((ldIn(gc_b, i, bf) - gm) * sg + gb - m2) * s2 + b2;
        }
    }

    #pragma unroll
    for (int e = 0; e < 2; ++e) {
        int i = (blk * 256 + t) * 2 + e;
        if (i < 262144) {
            Wgb[i] = (short)f2b(ldIn(wg, i, bf));
        } else if (i < 393216) {
            int j = i - 262144;
            W2b[j] = (short)f2b(ldIn(w2, j, bf));
        }
    }
}

// ---------------------------------------------------------------------------
// fc1 (VALU fp32 — the 6/6-verified numeric path, R10 verbatim):
//   Ft[b][n][c] = s1[c]*sum_k w[c][k]*x[b][k][n] + t1[c]
// 64x64 tile, 4x4/thread. Node-major fp32 output. grid (16,4,16).
// DO NOT change to MFMA: Ft must match the reference's fp32 F closely
// enough to preserve a near-degenerate kNN tie (R7/R12-R14 evidence).
// ---------------------------------------------------------------------------
__global__ __launch_bounds__(256)
void fc1_valu(const void* __restrict__ Aw, const void* __restrict__ Bx,
              float* __restrict__ Ft, const float* __restrict__ s1,
              const float* __restrict__ t1, const int* __restrict__ flags)
{
    __shared__ float As[16][68];
    __shared__ float Bs[16][68];

    int inf = flags[0];
    int b  = blockIdx.z;
    int o0 = blockIdx.y * 64, n0 = blockIdx.x * 64;
    int t  = threadIdx.x;
    int tn = t & 15, to = t >> 4;
    long long bbase = (long long)b * C_ * N_;

    float acc[4][4] = {};

    for (int k0 = 0; k0 < C_; k0 += 16) {
        {
            int l = t * 4;
            int ao = l >> 4, ak = l & 15;
            long long ai = (long long)(o0 + ao) * C_ + k0 + ak;
            As[ak + 0][ao] = ldIn(Aw, ai + 0, inf);
            As[ak + 1][ao] = ldIn(Aw, ai + 1, inf);
            As[ak + 2][ao] = ldIn(Aw, ai + 2, inf);
            As[ak + 3][ao] = ldIn(Aw, ai + 3, inf);
        }
        {
            int l = t * 4;
            int bk = l >> 6, bn = l & 63;
            long long bi = bbase + (long long)(k0 + bk) * N_ + n0 + bn;
            Bs[bk][bn + 0] = ldIn(Bx, bi + 0, inf);
            Bs[bk][bn + 1] = ldIn(Bx, bi + 1, inf);
            Bs[bk][bn + 2] = ldIn(Bx, bi + 2, inf);
            Bs[bk][bn + 3] = ldIn(Bx, bi + 3, inf);
        }
        __syncthreads();
        #pragma unroll
        for (int k = 0; k < 16; ++k) {
            float av[4], bv[4];
            #pragma unroll
            for (int i = 0; i < 4; ++i) av[i] = As[k][to * 4 + i];
            #pragma unroll
            for (int j = 0; j < 4; ++j) bv[j] = Bs[k][tn * 4 + j];
            #pragma unroll
            for (int i = 0; i < 4; ++i)
                #pragma unroll
                for (int j = 0; j < 4; ++j) acc[i][j] += av[i] * bv[j];
        }
        __syncthreads();
    }

    #pragma unroll
    for (int i = 0; i < 4; ++i) {
        int o = o0 + to * 4 + i;
        float s = s1[o], tt = t1[o];
        #pragma unroll
        for (int j = 0; j < 4; ++j) {
            int n = n0 + tn * 4 + j;
            Ft[((long long)(b << 10) + n) * C_ + o] = acc[i][j] * s + tt;
        }
    }
}

// ---------------------------------------------------------------------------
// prep_F (R10 verbatim — deterministic): Ft fp32 [n][c] -> Fhi/Flo bf16
// split + x2[n] = sum_c Ft^2 (fixed-order shuffle tree).
// grid (N/4, B), block 256 = 4 waves; wave per n, lane covers 4 c.
// ---------------------------------------------------------------------------
__global__ __launch_bounds__(256)
void prep_F(const float* __restrict__ Ft, short* __restrict__ Fhi,
            short* __restrict__ Flo, float* __restrict__ x2)
{
    int t = threadIdx.x;
    int wv = t >> 6, lane = t & 63;
    int n = blockIdx.x * 4 + wv;
    int b = blockIdx.y;
    long long base = ((long long)(b << 10) + n) * C_ + lane * 4;
    f4v f = *(const f4v*)(Ft + base);

    s4v hi, lo;
    #pragma unroll
    for (int r = 0; r < 4; ++r) {
        unsigned short h = f2b(f[r]);
        hi[r] = (short)h;
        lo[r] = (short)f2b(f[r] - b2f(h));
    }
    *(s4v*)(Fhi + base) = hi;
    *(s4v*)(Flo + base) = lo;

    float ss = f[0]*f[0] + f[1]*f[1] + f[2]*f[2] + f[3]*f[3];
    #pragma unroll
    for (int s = 32; s >= 1; s >>= 1) ss += __shfl_xor(ss, s, 64);
    if (lane == 0) x2[(b << 10) + n] = ss;
}

// ---------------------------------------------------------------------------
// Fused gram + top-9 v4 (UNCHANGED — verified R11+).
// ---------------------------------------------------------------------------
__global__ __launch_bounds__(256)
void gram_topk(const short* __restrict__ Fhi, const short* __restrict__ Flo,
               const float* __restrict__ x2, u64* __restrict__ Part)
{
    __shared__ __align__(16) char ldsbuf[31232];
    short* Ah  = (short*)(ldsbuf);
    short* Al  = (short*)(ldsbuf + 10240);
    short* Bh  = (short*)(ldsbuf + 20480);
    short* Bl  = (short*)(ldsbuf + 25600);
    float* x2s = (float*)(ldsbuf + 30720);
    u64*   mrg  = (u64*)(ldsbuf);
    u64*   mrg2 = (u64*)(ldsbuf + 20480);

    int t = threadIdx.x;
    int q0 = blockIdx.x * 64, mq = blockIdx.y, b = blockIdx.z;
    int wv = t >> 6, ln15 = t & 15, quad = (t >> 4) & 3;

    if (t < 128) x2s[t] = x2[(b << 10) + mq * 128 + t];

    f4v acc[8];
    #pragma unroll
    for (int i = 0; i < 8; ++i) acc[i] = 0.f;

    for (int kc = 0; kc < 8; ++kc) {
        __syncthreads();
        #pragma unroll
        for (int s = 0; s < 6; ++s) {
            int sid = t + s * 256;
            int row = sid >> 2, seg = sid & 3;
            const short* src;
            short* dst;
            int grow;
            if (row < 128)      { dst = &Ah[row * 40 + seg * 8];         grow = mq * 128 + row;       src = Fhi; }
            else if (row < 256) { dst = &Al[(row - 128) * 40 + seg * 8]; grow = mq * 128 + row - 128; src = Flo; }
            else if (row < 320) { dst = &Bh[(row - 256) * 40 + seg * 8]; grow = q0 + row - 256;       src = Fhi; }
            else                { dst = &Bl[(row - 320) * 40 + seg * 8]; grow = q0 + row - 320;       src = Flo; }
            *(s8v*)dst = *(const s8v*)(src + ((long long)((b << 10) + grow)) * C_ + kc * 32 + seg * 8);
        }
        __syncthreads();
        s8v qh = *(s8v*)&Bh[(wv * 16 + ln15) * 40 + quad * 8];
        s8v ql = *(s8v*)&Bl[(wv * 16 + ln15) * 40 + quad * 8];
        #pragma unroll
        for (int i = 0; i < 8; ++i) {
            s8v mh = *(s8v*)&Ah[(i * 16 + ln15) * 40 + quad * 8];
            s8v ml = *(s8v*)&Al[(i * 16 + ln15) * 40 + quad * 8];
            acc[i] = __builtin_amdgcn_mfma_f32_16x16x32_bf16(mh, qh, acc[i], 0, 0, 0);
            acc[i] = __builtin_amdgcn_mfma_f32_16x16x32_bf16(mh, ql, acc[i], 0, 0, 0);
            acc[i] = __builtin_amdgcn_mfma_f32_16x16x32_bf16(ml, qh, acc[i], 0, 0, 0);
        }
    }

    u64 l[9];
    #pragma unroll
    for (int i = 0; i < 9; ++i) l[i] = ~0ULL;
    #pragma unroll
    for (int i = 0; i < 8; ++i) {
        #pragma unroll
        for (int r = 0; r < 4; ++r) {
            int mloc = i * 16 + quad * 4 + r;
            float d = x2s[mloc] - 2.f * acc[i][r];
            unsigned u = __float_as_uint(d);
            u = (u & 0x80000000u) ? ~u : (u | 0x80000000u);
            u64 key = ((u64)u << 32) | (unsigned)(mq * 128 + mloc);
            if (key < l[8]) {
                u64 x = key;
                #pragma unroll
                for (int jj = 0; jj < 9; ++jj) {
                    u64 lo2 = l[jj] < x ? l[jj] : x;
                    u64 hi2 = l[jj] < x ? x : l[jj];
                    l[jj] = lo2; x = hi2;
                }
            }
        }
    }

    __syncthreads();
    {
        int qloc = wv * 16 + ln15;
        #pragma unroll
        for (int k = 0; k < 9; ++k) mrg[(qloc * 4 + quad) * 9 + k] = l[k];
    }
    __syncthreads();
    if (t < 128) {
        int r = t >> 1, pr = t & 1;
        const u64* LA = &mrg[(r * 4 + pr * 2) * 9];
        const u64* LB = LA + 9;
        int ia = 0, ib = 0;
        u64* Po = &mrg2[(r * 2 + pr) * 9];
        #pragma unroll
        for (int k = 0; k < 9; ++k) {
            u64 va = LA[ia], vb = LB[ib];
            bool ta = va < vb;
            Po[k] = ta ? va : vb;
            ia += ta; ib += !ta;
        }
    }
    __syncthreads();
    if (t < 64) {
        const u64* LA = &mrg2[(t * 2) * 9];
        const u64* LB = LA + 9;
        int ia = 0, ib = 0;
        u64* P = Part + (((long long)((b << 10) + q0 + t)) * 8 + mq) * 9;
        #pragma unroll
        for (int k = 0; k < 9; ++k) {
            u64 va = LA[ia], vb = LB[ib];
            bool ta = va < vb;
            P[k] = ta ? va : vb;
            ia += ta; ib += !ta;
        }
    }
}

// ---------------------------------------------------------------------------
// build_Mt + fused 8-list merge (UNCHANGED — verified R11+).
// ---------------------------------------------------------------------------
__global__ __launch_bounds__(256)
void build_Mt(const float* __restrict__ Ft, const u64* __restrict__ Part,
              short* __restrict__ Mt)
{
    int t = threadIdx.x;
    int wv = t >> 6, lane = t & 63;
    int n = blockIdx.x * 4 + wv;
    int b = blockIdx.y;
    long long nb = (long long)(b << 10) + n;

    const u64* L = Part + nb * 72 + (long long)(lane & 7) * 9;
    u64 l[9];
    #pragma unroll
    for (int k = 0; k < 9; ++k) l[k] = L[k];
    #pragma unroll
    for (int s = 1; s <= 4; s <<= 1) {
        u64 p[9];
        #pragma unroll
        for (int k = 0; k < 9; ++k) p[k] = shfl_xor_u64(l[k], s);
        #pragma unroll
        for (int k = 0; k < 9; ++k) {
            u64 x = p[k];
            if (x < l[8]) {
                #pragma unroll
                for (int jj = 0; jj < 9; ++jj) {
                    u64 lo2 = l[jj] < x ? l[jj] : x;
                    u64 hi2 = l[jj] < x ? x : l[jj];
                    l[jj] = lo2; x = hi2;
                }
            }
        }
    }

    int c0 = lane * 4;
    f4v f = *(const f4v*)(Ft + nb * C_ + c0);
    f4v mx = {-3.4e38f, -3.4e38f, -3.4e38f, -3.4e38f};
    #pragma unroll
    for (int k = 0; k < 9; ++k) {
        int id = (int)(l[k] & 0xFFFFFFFFu);
        f4v g = *(const f4v*)(Ft + ((long long)(b << 10) + id) * C_ + c0);
        mx[0] = fmaxf(mx[0], g[0]); mx[1] = fmaxf(mx[1], g[1]);
        mx[2] = fmaxf(mx[2], g[2]); mx[3] = fmaxf(mx[3], g[3]);
    }
    s8v m8;
    #pragma unroll
    for (int r = 0; r < 4; ++r) {
        m8[2 * r]     = (short)f2b(f[r]);
        m8[2 * r + 1] = (short)f2b(mx[r] - f[r]);
    }
    *(s8v*)(Mt + nb * (2 * C_) + 2 * c0) = m8;
}

// ---------------------------------------------------------------------------
// MFMA GEMM 64o x 64n (R13 retile — value-identical kc order, verified
// first-pass R13). EPI 0: gelu -> bf16 Gt; EPI 1: +resid -> fp32 out.
// ---------------------------------------------------------------------------
template<int EPI>
__global__ __launch_bounds__(256)
void mfma_gemm(const short* __restrict__ A, const short* __restrict__ Bm,
               void* __restrict__ Out, const float* __restrict__ scale,
               const float* __restrict__ bias, const void* __restrict__ resid,
               const int* __restrict__ flags, int K, int Odim)
{
    __shared__ __align__(16) short As[64 * 40];
    __shared__ __align__(16) short Bs[64 * 40];

    int t = threadIdx.x, b = blockIdx.z;
    int n0 = blockIdx.x * 64, o0 = blockIdx.y * 64;
    int wv = t >> 6, ln15 = t & 15, quad = (t >> 4) & 3;

    f4v acc[4];
    #pragma unroll
    for (int i = 0; i < 4; ++i) acc[i] = 0.f;

    int nkc = K >> 5;
    for (int kc = 0; kc < nkc; ++kc) {
        __syncthreads();
        #pragma unroll
        for (int s = 0; s < 2; ++s) {
            int sid = t + s * 256;
            int row = (sid >> 2) & 63, seg = sid & 3;
            if (s == 0)
                *(s8v*)&As[row * 40 + seg * 8] =
                    *(const s8v*)(A + (long long)(o0 + row) * K + kc * 32 + seg * 8);
            else
                *(s8v*)&Bs[row * 40 + seg * 8] =
                    *(const s8v*)(Bm + ((long long)((b << 10) + n0 + row)) * K + kc * 32 + seg * 8);
        }
        __syncthreads();
        s8v bf = *(s8v*)&Bs[(wv * 16 + ln15) * 40 + quad * 8];
        #pragma unroll
        for (int i = 0; i < 4; ++i) {
            s8v a = *(s8v*)&As[(i * 16 + ln15) * 40 + quad * 8];
            acc[i] = __builtin_amdgcn_mfma_f32_16x16x32_bf16(a, bf, acc[i], 0, 0, 0);
        }
    }

    int inf = flags[0];
    int n = n0 + wv * 16 + ln15;
    #pragma unroll
    for (int i = 0; i < 4; ++i) {
        int ob = o0 + i * 16 + quad * 4;
        if (EPI == 0) {
            s4v g;
            #pragma unroll
            for (int r = 0; r < 4; ++r) {
                float val = acc[i][r] * scale[ob + r] + bias[ob + r];
                val = 0.5f * val * (1.0f + erff(val * 0.70710678118654752f));
                g[r] = (short)f2b(val);
            }
            *(s4v*)((short*)Out + ((long long)((b << 10) + n)) * Odim + ob) = g;
        } else {
            #pragma unroll
            for (int r = 0; r < 4; ++r) {
                int o = ob + r;
                long long oi = ((long long)b * Odim + o) * N_ + n;
                ((float*)Out)[oi] = acc[i][r] * scale[o] + bias[o] + ldIn(resid, oi, inf);
            }
        }
    }
}

// ---------------------------------------------------------------------------
extern "C" void kernel_launch(void* const* d_in, const int* in_sizes, int n_in,
                              void* d_out, int out_size, void* d_ws, size_t ws_size,
                              hipStream_t stream)
{
    const void* p[23];
    if (n_in >= 23 && in_sizes[0] != 4194304 && in_sizes[22] == 4194304) {
        const int amap[23] = {
            22, 13, 12, 1, 0, 2, 3,
            21, 20, 17, 16, 18, 19,
            5, 4, 6, 7,
            15, 14, 9, 8, 10, 11 };
        for (int i = 0; i < 23; ++i) p[i] = d_in[amap[i]];
    } else {
        for (int i = 0; i < 23; ++i) p[i] = d_in[i];
    }

    const void* x     = p[0];
    const void* fc1_w = p[1];
    const void* fc1_b = p[2];
    const void* bn1_g = p[3];
    const void* bn1_b = p[4];
    const void* bn1_m = p[5];
    const void* bn1_v = p[6];
    const void* gc_w  = p[7];
    const void* gc_b  = p[8];
    const void* gbn_g = p[9];
    const void* gbn_b = p[10];
    const void* gbn_m = p[11];
    const void* gbn_v = p[12];
    const void* bn2_g = p[13];
    const void* bn2_b = p[14];
    const void* bn2_m = p[15];
    const void* bn2_v = p[16];
    const void* fc2_w = p[17];
    const void* fc2_b = p[18];
    const void* bn3_g = p[19];
    const void* bn3_b = p[20];
    const void* bn3_m = p[21];
    const void* bn3_v = p[22];

    char* ws = (char*)d_ws;
    size_t off = 0;
    int*   flags = (int*)ws;
    float* s1 = (float*)(ws + 256);
    float* t1 = s1 + 256;
    float* s3 = t1 + 256;
    float* t3 = s3 + 256;
    float* Sg = t3 + 256;
    float* Tg = Sg + 512;
    off = 16384;
    short* Wgb   = (short*)(ws + off); off += (size_t)HID_ * 2 * C_ * 2;    // 512 KiB
    short* W2b   = (short*)(ws + off); off += (size_t)C_ * HID_ * 2;        // 256 KiB
    float* Ft    = (float*)(ws + off); off += (size_t)B_ * N_ * C_ * 4;     // 16 MiB
    short* Fhi   = (short*)(ws + off); off += (size_t)B_ * N_ * C_ * 2;     // 8 MiB
    short* Flo   = (short*)(ws + off); off += (size_t)B_ * N_ * C_ * 2;     // 8 MiB
    float* x2    = (float*)(ws + off); off += (size_t)B_ * N_ * 4;          // 64 KiB
    u64*   Part  = (u64*)  (ws + off); off += (size_t)B_ * N_ * 8 * 9 * 8;  // 9 MiB
    short* Mt    = (short*)(ws + off); off += (size_t)B_ * N_ * 2 * C_ * 2; // 16 MiB
    short* Gt    = (short*)(ws + off); off += (size_t)B_ * N_ * HID_ * 2;   // 16 MiB

    prep_cast<<<768, 256, 0, stream>>>(x,
        gc_w, fc2_w,
        fc1_b, bn1_g, bn1_b, bn1_m, bn1_v,
        gc_b, gbn_g, gbn_b, gbn_m, gbn_v,
        bn2_g, bn2_b, bn2_m, bn2_v,
        fc2_b, bn3_g, bn3_b, bn3_m, bn3_v,
        flags, s1, t1, Sg, Tg, s3, t3,
        Wgb, W2b);

    // fc1 + BN1 -> Ft fp32 (6/6-verified numeric path)
    fc1_valu<<<dim3(16, 4, B_), 256, 0, stream>>>(fc1_w, x, Ft, s1, t1, flags);

    // Ft -> Fhi/Flo + x2 (deterministic)
    prep_F<<<dim3(N_ / 4, B_), 256, 0, stream>>>(Ft, Fhi, Flo, x2);

    gram_topk<<<dim3(16, 8, 16), 256, 0, stream>>>(Fhi, Flo, x2, Part);

    build_Mt<<<dim3(256, 16), 256, 0, stream>>>(Ft, Part, Mt);

    mfma_gemm<0><<<dim3(16, 8, 16), 256, 0, stream>>>(
        Wgb, Mt, Gt, Sg, Tg, nullptr, flags, 2 * C_, HID_);

    mfma_gemm<1><<<dim3(16, 4, 16), 256, 0, stream>>>(
        W2b, Gt, d_out, s3, t3, x, flags, HID_, C_);
}